// Round 4
// baseline (46.683 us; speedup 1.0000x reference)
//
#include <hip/hip_runtime.h>

// Problem constants (AdaptivePruner)
#define NB   256   // batch
#define NTOK 197   // tokens incl cls
#define NP   196   // patch tokens
#define ND   768   // channels
#define LEN1 101   // one-level DWT length
#define LEN2 54    // two-level DWT length
#define OUTROWS 102
#define QROWS 8               // output rows per block
#define NQ   13               // ceil(102/8)
#define NWG  (NB * NQ)        // 3328, divisible by 8

typedef float f4 __attribute__((ext_vector_type(4)));

// ---------------- Gini kernel: one block per batch row ----------------
// gini = 2*sum(rank_i*p_i)/(N*sum(p)+1e-8) - (N+1)/N, rank ascending 1-based.
// Rank by counting (tie-order irrelevant to the sum); double accumulation.
// Decision arithmetic identical to the previously-passing version.
__global__ __launch_bounds__(256)
void gini_kernel(const float* __restrict__ attn, int* __restrict__ flags) {
    __shared__ __align__(16) float row[NP];
    __shared__ double wS[4], wT[4];
    const int b   = blockIdx.x;
    const int tid = threadIdx.x;
    if (tid < NP) row[tid] = attn[b * NP + tid];
    __syncthreads();
    double sj = 0.0, tj = 0.0;
    if (tid < NP) {
        const float p = row[tid];
        int rank = 1;
        #pragma unroll 7
        for (int k4 = 0; k4 < NP / 4; ++k4) {         // 49 f4 iterations
            const f4 qv = *(const f4*)&row[4 * k4];
            #pragma unroll
            for (int e = 0; e < 4; ++e) {
                const float qe = qv[e];
                const int idx = 4 * k4 + e;
                rank += (qe < p) || (qe == p && idx < tid);
            }
        }
        sj = (double)rank * (double)p;
        tj = (double)p;
    }
    #pragma unroll
    for (int off = 32; off > 0; off >>= 1) {
        sj += __shfl_down(sj, off);
        tj += __shfl_down(tj, off);
    }
    const int wid = tid >> 6, lane = tid & 63;
    if (lane == 0) { wS[wid] = sj; wT[wid] = tj; }
    __syncthreads();
    if (tid == 0) {
        const double S = wS[0] + wS[1] + wS[2] + wS[3];
        const double T = wT[0] + wT[1] + wT[2] + wT[3];
        const double gini = 2.0 * S / ((double)NP * T + 1e-8)
                          - (double)(NP + 1) / (double)NP;
        flags[b] = (gini > (double)0.333f) ? 1 : 0;
    }
}

// ---------------- Main DWT kernel ----------------
// One block (192 threads) per (batch, 8-output-row group). Each thread owns
// one float4 channel column. Loads stream once through the shared input
// window, accumulating on the fly into 8 f4 accumulators (no window array).
__global__ __launch_bounds__(192)
void dwt_kernel(const float* __restrict__ x, const int* __restrict__ flags,
                float* __restrict__ out_x, float* __restrict__ out_mask) {
    const float h[8] = {0.23037781330885523f,  0.7148465705525415f,
                        0.6308807679295904f,  -0.02798376941698385f,
                       -0.18703481171888114f,  0.030841381835986965f,
                        0.032883011666982945f,-0.010597401784997278f};
    // composite two-level filter g2[m] = sum_{2j+l=m} h[j]*h[l] (constant-folded)
    float g2[22];
    #pragma unroll
    for (int m = 0; m < 22; ++m) {
        float s = 0.f;
        #pragma unroll
        for (int j = 0; j < 8; ++j) {
            const int l = m - 2 * j;
            if (0 <= l && l < 8) s += h[j] * h[l];
        }
        g2[m] = s;
    }

    // XCD-aware bijective swizzle (NWG % 8 == 0)
    const int hw  = blockIdx.x;
    const int per = NWG / 8;                 // 416
    const int bid = (hw & 7) * per + (hw >> 3);
    const int b   = bid / NQ;
    const int q   = bid - b * NQ;            // 0..12: rows 8q .. 8q+7
    const int c   = threadIdx.x;             // channel float4 group
    const int d0  = c * 4;

    const float* __restrict__ px = x + ((size_t)b * NTOK + 1) * ND + d0; // patch[0]
    float* __restrict__ po = out_x + (size_t)b * OUTROWS * ND + d0;
    const int flag  = flags[b];
    const int rbase = q * QROWS;
    const int jmax  = (rbase + QROWS <= OUTROWS) ? QROWS : (OUTROWS - rbase);

    f4 acc[QROWS];
    #pragma unroll
    for (int j = 0; j < QROWS; ++j) acc[j] = (f4){0.f, 0.f, 0.f, 0.f};

    auto raw = [&](int i) -> f4 { return *(const f4*)(px + (size_t)i * ND); };
    auto clamped = [&](int i) -> f4 {
        return (i >= 0 && i < NP) ? *(const f4*)(px + (size_t)i * ND)
                                  : (f4){0.f, 0.f, 0.f, 0.f};
    };

    if (!flag) {
        // rows r=8q+j -> t = 8q-1+j ; y1[t] = sum_l h[l]*xp(2t-6+l)
        // window i in [16q-8, 16q+13], l = k - 2j
        const int lo = 16 * q - 8;
        auto run = [&](auto ld) {
            #pragma unroll
            for (int k = 0; k < 22; ++k) {
                const f4 v = ld(lo + k);
                #pragma unroll
                for (int j = 0; j < QROWS; ++j) {
                    const int l = k - 2 * j;
                    if (0 <= l && l < 8) acc[j] += h[l] * v;
                }
            }
        };
        if (q >= 1 && q <= 11) run(raw); else run(clamped);
    } else if (q <= 6) {
        // rows r=8q+j -> s = 8q-1+j ; y2[s] = sum_m g2[m]*xp(4s-18+m)
        // window i in [32q-22, 32q+27], m = k - 4j
        // (s>=54 rows come out zero naturally: all indices >=196 clamp to 0)
        const int lo = 32 * q - 22;
        auto run = [&](auto ld) {
            #pragma unroll
            for (int k = 0; k < 50; ++k) {
                const f4 v = ld(lo + k);
                #pragma unroll
                for (int j = 0; j < QROWS; ++j) {
                    const int m = k - 4 * j;
                    if (0 <= m && m < 22) acc[j] += g2[m] * v;
                }
            }
        };
        if (q >= 1 && q <= 5) run(raw); else run(clamped);
    }
    // flag=1, q>=7: pure pad rows, acc stays zero

    if (q == 0) {
        // row 0: cls passthrough; also the per-batch mask
        acc[0] = *(const f4*)(x + (size_t)b * NTOK * ND + d0);
        if (c < OUTROWS) {
            const int outlen = flag ? LEN2 : LEN1;
            out_mask[b * OUTROWS + c] = (c == 0 || (c - 1) < outlen) ? 1.0f : 0.0f;
        }
    }

    #pragma unroll
    for (int j = 0; j < QROWS; ++j)
        if (j < jmax)
            __builtin_nontemporal_store(acc[j], (f4*)(po + (size_t)(rbase + j) * ND));
}

extern "C" void kernel_launch(void* const* d_in, const int* in_sizes, int n_in,
                              void* d_out, int out_size, void* d_ws, size_t ws_size,
                              hipStream_t stream) {
    const float* x    = (const float*)d_in[0];  // (256,197,768) f32
    const float* attn = (const float*)d_in[1];  // (256,196) f32
    float* out_x    = (float*)d_out;                             // (256,102,768)
    float* out_mask = (float*)d_out + (size_t)NB * OUTROWS * ND; // (256,102)
    int* flags = (int*)d_ws;                                     // 256 ints

    gini_kernel<<<NB, 256, 0, stream>>>(attn, flags);
    dwt_kernel<<<NWG, 192, 0, stream>>>(x, flags, out_x, out_mask);
}

// Round 5
// 44.471 us; speedup vs baseline: 1.0497x; 1.0497x over previous
//
#include <hip/hip_runtime.h>

// Problem constants (AdaptivePruner)
#define NB   256   // batch
#define NTOK 197   // tokens incl cls
#define NP   196   // patch tokens
#define ND   768   // channels
#define LEN1 101   // one-level DWT length
#define LEN2 54    // two-level DWT length
#define OUTROWS 102
#define NGRP 51               // row-pairs per batch (102 rows / 2)
#define NWG  (NB * NGRP)      // 13056, divisible by 8

typedef float f4 __attribute__((ext_vector_type(4)));

// ---------------- Gini kernel: one block per batch row ----------------
// gini = 2*sum(rank_i*p_i)/(N*sum(p)+1e-8) - (N+1)/N, rank ascending 1-based.
// Rank by counting (tie-order irrelevant to the sum); double accumulation.
__global__ __launch_bounds__(256)
void gini_kernel(const float* __restrict__ attn, int* __restrict__ flags) {
    __shared__ float  row[NP];
    __shared__ double sS[256];
    __shared__ double sT[256];
    const int b   = blockIdx.x;
    const int tid = threadIdx.x;
    if (tid < NP) row[tid] = attn[b * NP + tid];
    __syncthreads();
    double sj = 0.0, tj = 0.0;
    if (tid < NP) {
        const float p = row[tid];
        int rank = 1;
        for (int k = 0; k < NP; ++k) {
            const float q = row[k];
            rank += (q < p) || (q == p && k < tid);
        }
        sj = (double)rank * (double)p;
        tj = (double)p;
    }
    sS[tid] = sj; sT[tid] = tj;
    __syncthreads();
    for (int off = 128; off > 0; off >>= 1) {
        if (tid < off) { sS[tid] += sS[tid + off]; sT[tid] += sT[tid + off]; }
        __syncthreads();
    }
    if (tid == 0) {
        const double S = sS[0], T = sT[0];
        const double gini = 2.0 * S / ((double)NP * T + 1e-8)
                          - (double)(NP + 1) / (double)NP;
        flags[b] = (gini > (double)0.333f) ? 1 : 0;
    }
}

// ---------------- Main DWT kernel ----------------
// One block (192 threads) per output ROW-PAIR (b, rows 2g & 2g+1).
// Each thread owns one float4 channel group; register window per pair.
// Plain (cached) stores: out fits LLC alongside x -> write absorption.
__global__ __launch_bounds__(192)
void dwt_kernel(const float* __restrict__ x, const int* __restrict__ flags,
                float* __restrict__ out_x, float* __restrict__ out_mask) {
    const float h[8] = {0.23037781330885523f,  0.7148465705525415f,
                        0.6308807679295904f,  -0.02798376941698385f,
                       -0.18703481171888114f,  0.030841381835986965f,
                        0.032883011666982945f,-0.010597401784997278f};
    // composite two-level filter g2[m] = sum_{2j+l=m} h[j]*h[l] (constant-folded)
    float g2[22];
    #pragma unroll
    for (int m = 0; m < 22; ++m) {
        float s = 0.f;
        #pragma unroll
        for (int j = 0; j < 8; ++j) {
            const int l = m - 2 * j;
            if (0 <= l && l < 8) s += h[j] * h[l];
        }
        g2[m] = s;
    }

    // XCD-aware bijective swizzle (NWG % 8 == 0)
    const int hw  = blockIdx.x;
    const int per = NWG / 8;                 // 1632
    const int bid = (hw & 7) * per + (hw >> 3);
    const int b   = bid / NGRP;
    const int grp = bid - b * NGRP;          // 0..50
    const int c   = threadIdx.x;             // channel float4 group
    const int d0  = c * 4;

    const float* __restrict__ px = x + ((size_t)b * NTOK + 1) * ND + d0; // patch[0]
    float* __restrict__ po = out_x + (size_t)b * OUTROWS * ND + d0;
    const int flag = flags[b];

    auto loadx = [&](int i) -> f4 {
        if (i < 0 || i >= NP) return (f4){0.f, 0.f, 0.f, 0.f};
        return *(const f4*)(px + (size_t)i * ND);
    };

    if (grp == 0) {
        // row 0: cls passthrough (+ mask), row 1: first output row
        const f4 cls = *(const f4*)(x + (size_t)b * NTOK * ND + d0);
        *(f4*)po = cls;
        if (c < OUTROWS) {
            const int outlen = flag ? LEN2 : LEN1;
            out_mask[b * OUTROWS + c] = (c == 0 || (c - 1) < outlen) ? 1.0f : 0.0f;
        }
        f4 y = {0.f, 0.f, 0.f, 0.f};
        if (!flag) {
            // t=0: i = -6+l, valid l=6,7 -> i=0,1
            y += h[6] * loadx(0);
            y += h[7] * loadx(1);
        } else {
            // s=0: i = -18+m, valid m=18..21 -> i=0..3
            #pragma unroll
            for (int m = 18; m < 22; ++m) y += g2[m] * loadx(m - 18);
        }
        *(f4*)(po + (size_t)ND) = y;
        return;
    }

    if (!flag) {
        // rows 2g, 2g+1  <->  t0 = 2g-1, t1 = 2g ; window i in [4g-8, 4g+1]
        const int lo = 4 * grp - 8;
        f4 w[10];
        if (grp >= 2 && grp <= 48) {
            #pragma unroll
            for (int k = 0; k < 10; ++k) w[k] = *(const f4*)(px + (size_t)(lo + k) * ND);
        } else {
            #pragma unroll
            for (int k = 0; k < 10; ++k) w[k] = loadx(lo + k);
        }
        f4 y0 = {0.f,0.f,0.f,0.f}, y1 = {0.f,0.f,0.f,0.f};
        #pragma unroll
        for (int l = 0; l < 8; ++l) {
            y0 += h[l] * w[l];
            y1 += h[l] * w[l + 2];
        }
        *(f4*)(po + (size_t)(2 * grp) * ND) = y0;
        *(f4*)(po + (size_t)(2 * grp + 1) * ND) = y1;
    } else {
        const int s0 = 2 * grp - 1;          // rows 2g (=1+s0), 2g+1 (=1+s0+1)
        if (s0 < LEN2) {
            // window i in [4*s0-18, 4*s0+7] = [8g-22, 8g+3], 26 rows
            const int lo = 8 * grp - 22;
            f4 w[26];
            if (grp >= 3 && grp <= 24) {
                #pragma unroll
                for (int k = 0; k < 26; ++k) w[k] = *(const f4*)(px + (size_t)(lo + k) * ND);
            } else {
                #pragma unroll
                for (int k = 0; k < 26; ++k) w[k] = loadx(lo + k);
            }
            f4 y0 = {0.f,0.f,0.f,0.f}, y1 = {0.f,0.f,0.f,0.f};
            #pragma unroll
            for (int m = 0; m < 22; ++m) {
                y0 += g2[m] * w[m];
                y1 += g2[m] * w[m + 4];
            }
            if (s0 + 1 >= LEN2) y1 = (f4){0.f,0.f,0.f,0.f};   // row 55 is pad
            *(f4*)(po + (size_t)(2 * grp) * ND) = y0;
            *(f4*)(po + (size_t)(2 * grp + 1) * ND) = y1;
        } else {
            const f4 zero = {0.f,0.f,0.f,0.f};
            *(f4*)(po + (size_t)(2 * grp) * ND) = zero;
            *(f4*)(po + (size_t)(2 * grp + 1) * ND) = zero;
        }
    }
}

extern "C" void kernel_launch(void* const* d_in, const int* in_sizes, int n_in,
                              void* d_out, int out_size, void* d_ws, size_t ws_size,
                              hipStream_t stream) {
    const float* x    = (const float*)d_in[0];  // (256,197,768) f32
    const float* attn = (const float*)d_in[1];  // (256,196) f32
    float* out_x    = (float*)d_out;                             // (256,102,768)
    float* out_mask = (float*)d_out + (size_t)NB * OUTROWS * ND; // (256,102)
    int* flags = (int*)d_ws;                                     // 256 ints

    gini_kernel<<<NB, 256, 0, stream>>>(attn, flags);
    dwt_kernel<<<NWG, 192, 0, stream>>>(x, flags, out_x, out_mask);
}